// Round 16
// baseline (126.939 us; speedup 1.0000x reference)
//
#include <hip/hip_runtime.h>
#include <hip/hip_bf16.h>

#define BZ 8192
#define PP 1024
#define DD 1024
#define KSEL 8

typedef unsigned short u16;
typedef unsigned long long u64;
typedef __attribute__((ext_vector_type(8))) short bf16x8;
typedef __attribute__((ext_vector_type(4))) float f32x4;

// ws layout (floats):
//   [0,1024)       inv-norm keys
//   [1024,9216)    inv-norm ppg
//   [9216,17408)   per-row top-8 score sum
//   [17408,25600)  per-row entropy
//   [25600,91136)  top-8 indices (ints)
//   byte 368640   .. 38117376 : bf16 A_hi, A_lo (16MB each), B_hi, B_lo (2MB each)
//   byte 38117376 .. 42311680 : pcnn = relu(conv(pool)) fp32 [1024][1024] (4MB)
//   (end == 42,311,680 == r1's proven WS_NEED gate -> fits ws_size)
// C (fp32 cos matrix) lives in d_out; topk reads it, prompt overwrites it.
#define WS_INVK 0
#define WS_INVP 1024
#define WS_SCORE 9216
#define WS_ENT 17408
#define WS_IDX 25600
#define WS_BF16_BYTE 368640ull
#define WS_PCNN_BYTE 38117376ull

__device__ __forceinline__ u16 f2bf(float x) {
  __hip_bfloat16 h = __float2bfloat16(x);
  return *(u16*)&h;
}
__device__ __forceinline__ float bf2f(u16 u) {
  __hip_bfloat16 h; *(u16*)&h = u;
  return __bfloat162float(h);
}
__device__ __forceinline__ void gll16(const void* g, void* l) {
  __builtin_amdgcn_global_load_lds((__attribute__((address_space(1))) void*)g,
                                   (__attribute__((address_space(3))) void*)l, 16, 0, 0);
}

// ---------- Kernel 1: fused fp32->bf16 hi/lo conversion + inverse norms ------
// (verbatim r3 — validated)
__global__ __launch_bounds__(256) void convert_kernel(const float* __restrict__ ppg,
                                                      const float* __restrict__ keys,
                                                      float* __restrict__ ws) {
  u16* Ahi = (u16*)((char*)ws + WS_BF16_BYTE);
  u16* Alo = Ahi + 8388608;
  u16* Bhi = Alo + 8388608;
  u16* Blo = Bhi + 1048576;

  int blk = blockIdx.x;
  const float* src; u16 *hi, *lo; float* invdst;
  if (blk < PP) {
    src = keys + (size_t)blk * DD;
    hi = Bhi + (size_t)blk * DD; lo = Blo + (size_t)blk * DD;
    invdst = ws + WS_INVK + blk;
  } else {
    int r = blk - PP;
    src = ppg + (size_t)r * DD;
    hi = Ahi + (size_t)r * DD; lo = Alo + (size_t)r * DD;
    invdst = ws + WS_INVP + r;
  }
  int t = threadIdx.x;
  float4 v = ((const float4*)src)[t];
  float x[4] = {v.x, v.y, v.z, v.w};
  u16 h4[4], l4[4];
  float s = 0.f;
  #pragma unroll
  for (int j = 0; j < 4; ++j) {
    h4[j] = f2bf(x[j]);
    l4[j] = f2bf(x[j] - bf2f(h4[j]));
    s += x[j] * x[j];
  }
  *(ushort4*)(hi + t * 4) = *(ushort4*)h4;
  *(ushort4*)(lo + t * 4) = *(ushort4*)l4;

  __shared__ float red[4];
  #pragma unroll
  for (int o = 32; o > 0; o >>= 1) s += __shfl_down(s, o);
  if ((t & 63) == 0) red[t >> 6] = s;
  __syncthreads();
  if (t == 0) {
    float tot = red[0] + red[1] + red[2] + red[3];
    *invdst = 1.0f / fmaxf(sqrtf(tot), 1e-8f);
  }
}

// ---------- Kernel 1b: pcnn = relu(conv(pool)) precompute -------------------
// Conv math verbatim from the validated prompt body (same fmaf nesting) ->
// bit-identical values to what prompt_kernel previously computed inline.
__global__ __launch_bounds__(256) void pcnn_kernel(const float* __restrict__ pool,
                                                   const float* __restrict__ cw,
                                                   const float* __restrict__ cb,
                                                   float* __restrict__ ws) {
  float* pcnn = (float*)((char*)ws + WS_PCNN_BYTE);
  int row = blockIdx.x;
  int t = threadIdx.x;
  int d0 = t * 4;
  const float* src = pool + (size_t)row * DD;
  float w0 = cw[0], w1 = cw[1], w2 = cw[2], bb = cb[0];

  f32x4 x = *(const f32x4*)(src + d0);
  float xm = (d0 > 0) ? src[d0 - 1] : 0.f;
  float xp = (d0 + 4 < DD) ? src[d0 + 4] : 0.f;
  float y0 = fmaf(w0, xm,   fmaf(w1, x[0], fmaf(w2, x[1], bb)));
  float y1 = fmaf(w0, x[0], fmaf(w1, x[1], fmaf(w2, x[2], bb)));
  float y2 = fmaf(w0, x[1], fmaf(w1, x[2], fmaf(w2, x[3], bb)));
  float y3 = fmaf(w0, x[2], fmaf(w1, x[3], fmaf(w2, xp,   bb)));
  f32x4 o4;
  o4[0] = fmaxf(y0, 0.f);
  o4[1] = fmaxf(y1, 0.f);
  o4[2] = fmaxf(y2, 0.f);
  o4[3] = fmaxf(y3, 0.f);
  *(f32x4*)(pcnn + (size_t)row * DD + d0) = o4;
}

// ---------- Kernel 2: 3-pass bf16 hi/lo MFMA GEMM -> fp32 cos in d_out ------
// r9-validated math; BK 64->32 (LDS 64->32 KB) for 2->4 blocks/CU occupancy.
#define LDS_AH 0
#define LDS_AL 4096
#define LDS_BH 8192
#define LDS_BL 12288

__global__ __launch_bounds__(256, 4) void gemm_mfma(const float* __restrict__ ws_ro,
                                                    float* __restrict__ C) {
  const u16* Ahi = (const u16*)((const char*)ws_ro + WS_BF16_BYTE);
  const u16* Alo = Ahi + 8388608;
  const u16* Bhi = Alo + 8388608;
  const u16* Blo = Bhi + 1048576;

  __shared__ u16 lds[16384];  // 32 KB: 4 arrays x 128x32 bf16

  int t = threadIdx.x;
  int wid = t >> 6, lane = t & 63;
  int lr = lane & 15, lg = lane >> 4;

  int orig = blockIdx.x;
  int wg = (orig & 7) * 64 + (orig >> 3);
  int bm0 = (wg >> 3) * 128;
  int bn0 = (wg & 7) * 128;
  int wm = wid >> 1, wn = wid & 1;

  // staging: 2 rounds, slot s = r*256+t -> row = s>>2, 16B-group g = s&3
  size_t offA[2], offB[2];
  int ldso[2];
  #pragma unroll
  for (int r = 0; r < 2; ++r) {
    int s = r * 256 + t;
    int row = s >> 2, g = s & 3;
    offA[r] = (size_t)(bm0 + row) * DD + g * 8;
    offB[r] = (size_t)(bn0 + row) * DD + g * 8;
    ldso[r] = (r * 256 + wid * 64) * 8;   // ushort idx of wave-uniform base
  }

  f32x4 acc[4][4] = {};

  for (int kt = 0; kt < 32; ++kt) {
    int k0 = kt * 32;
    #pragma unroll
    for (int r = 0; r < 2; ++r) {
      gll16(Ahi + offA[r] + k0, &lds[LDS_AH + ldso[r]]);
      gll16(Alo + offA[r] + k0, &lds[LDS_AL + ldso[r]]);
      gll16(Bhi + offB[r] + k0, &lds[LDS_BH + ldso[r]]);
      gll16(Blo + offB[r] + k0, &lds[LDS_BL + ldso[r]]);
    }
    __syncthreads();

    bf16x8 ah[4], al[4], bh[4], bl[4];
    #pragma unroll
    for (int i = 0; i < 4; ++i) {
      int off = (wm * 64 + i * 16 + lr) * 32 + lg * 8;
      ah[i] = *(const bf16x8*)&lds[LDS_AH + off];
      al[i] = *(const bf16x8*)&lds[LDS_AL + off];
    }
    #pragma unroll
    for (int j = 0; j < 4; ++j) {
      int off = (wn * 64 + j * 16 + lr) * 32 + lg * 8;
      bh[j] = *(const bf16x8*)&lds[LDS_BH + off];
      bl[j] = *(const bf16x8*)&lds[LDS_BL + off];
    }
    #pragma unroll
    for (int i = 0; i < 4; ++i)
      #pragma unroll
      for (int j = 0; j < 4; ++j) {
        acc[i][j] = __builtin_amdgcn_mfma_f32_16x16x32_bf16(ah[i], bh[j], acc[i][j], 0, 0, 0);
        acc[i][j] = __builtin_amdgcn_mfma_f32_16x16x32_bf16(ah[i], bl[j], acc[i][j], 0, 0, 0);
        acc[i][j] = __builtin_amdgcn_mfma_f32_16x16x32_bf16(al[i], bh[j], acc[i][j], 0, 0, 0);
      }
    __syncthreads();
  }

  const float* invP = ws_ro + WS_INVP;
  const float* invK = ws_ro + WS_INVK;
  #pragma unroll
  for (int i = 0; i < 4; ++i) {
    #pragma unroll
    for (int q = 0; q < 4; ++q) {
      int row = bm0 + wm * 64 + i * 16 + lg * 4 + q;
      float ip = invP[row];
      #pragma unroll
      for (int j = 0; j < 4; ++j) {
        int col = bn0 + wn * 64 + j * 16 + lr;
        C[(size_t)row * PP + col] = acc[i][j][q] * ip * invK[col];
      }
    }
  }
}

// ---------- Kernel 3: wave-per-row top-8 + entropy (u64 keys, r15-validated) -
__global__ __launch_bounds__(256) void topk_wave_kernel(const float* __restrict__ cosm,
                                                        float* __restrict__ ws) {
  int wid = threadIdx.x >> 6, lane = threadIdx.x & 63;
  int row = blockIdx.x * 4 + wid;
  const float* crow = cosm + (size_t)row * PP;

  float c[16];
  #pragma unroll
  for (int p = 0; p < 4; ++p) {
    f32x4 v = *(const f32x4*)(crow + p * 256 + lane * 4);
    c[p * 4 + 0] = v[0]; c[p * 4 + 1] = v[1]; c[p * 4 + 2] = v[2]; c[p * 4 + 3] = v[3];
  }

  float z = 0.f, w = 0.f;
  #pragma unroll
  for (int l = 0; l < 16; ++l) {
    float s = 1.0f - c[l];
    float e = __expf(s - 2.0f);
    z += e; w += s * e;
  }
  #pragma unroll
  for (int o = 1; o < 64; o <<= 1) { z += __shfl_xor(z, o); w += __shfl_xor(w, o); }
  if (lane == 0) ws[WS_ENT + row] = 2.0f + __logf(z) - w / z;

  u64 k[16];
  #pragma unroll
  for (int l = 0; l < 16; ++l) {
    unsigned fb = __builtin_bit_cast(unsigned, c[l]);
    unsigned mv = fb ^ ((unsigned)((int)fb >> 31) | 0x80000000u);
    int g = ((l >> 2) << 8) | (lane << 2) | (l & 3);
    k[l] = ((u64)mv << 10) | (unsigned)(1023 - g);
  }

  float score_sum = 0.f;
  int myidx = 0;
  #pragma unroll
  for (int it = 0; it < KSEL; ++it) {
    u64 m = k[0];
    #pragma unroll
    for (int l = 1; l < 16; ++l) m = (k[l] > m) ? k[l] : m;
    #pragma unroll
    for (int o = 1; o < 64; o <<= 1) {
      u64 p = __shfl_xor(m, o);
      m = (p > m) ? p : m;
    }
    unsigned mv2 = (unsigned)(m >> 10);
    unsigned fb2 = mv2 ^ ((mv2 & 0x80000000u) ? 0x80000000u : 0xFFFFFFFFu);
    score_sum += 1.0f - __builtin_bit_cast(float, fb2);
    if (lane == it) myidx = 1023 - (int)(m & 1023u);
    #pragma unroll
    for (int l = 0; l < 16; ++l) k[l] = (k[l] == m) ? 0ull : k[l];
  }
  if (lane == 0) ws[WS_SCORE + row] = score_sum;
  if (lane < KSEL) ((int*)(ws + WS_IDX))[row * KSEL + lane] = myidx;
}

// ---------- Kernel 4: block-per-row prompt (gathers precomputed pcnn) -------
// Same accumulation order as r9's validated body -> bit-identical output.
__global__ __launch_bounds__(256) void prompt_kernel(const float* __restrict__ ppg,
                                                     const float* __restrict__ ws_ro,
                                                     const float* __restrict__ ws,
                                                     float* __restrict__ out) {
  const float* pcnn = (const float*)((const char*)ws_ro + WS_PCNN_BYTE);
  int row = blockIdx.x;
  int t = threadIdx.x;
  const int* idx = (const int*)(ws + WS_IDX) + row * KSEL;
  int d0 = t * 4;

  float a0 = 0.f, a1 = 0.f, a2 = 0.f, a3 = 0.f;
  #pragma unroll
  for (int j = 0; j < KSEL; ++j) {
    int r = idx[j];
    f32x4 x = *(const f32x4*)(pcnn + (size_t)r * DD + d0);
    a0 += x[0]; a1 += x[1]; a2 += x[2]; a3 += x[3];
  }
  a0 *= 0.125f; a1 *= 0.125f; a2 *= 0.125f; a3 *= 0.125f;

  __shared__ float rmin[4], rmax[4];
  float lmin = fminf(fminf(a0, a1), fminf(a2, a3));
  float lmax = fmaxf(fmaxf(a0, a1), fmaxf(a2, a3));
  #pragma unroll
  for (int o = 32; o > 0; o >>= 1) {
    lmin = fminf(lmin, __shfl_down(lmin, o));
    lmax = fmaxf(lmax, __shfl_down(lmax, o));
  }
  if ((t & 63) == 0) { rmin[t >> 6] = lmin; rmax[t >> 6] = lmax; }
  __syncthreads();
  float pmin = fminf(fminf(rmin[0], rmin[1]), fminf(rmin[2], rmin[3]));
  float pmax = fmaxf(fmaxf(rmax[0], rmax[1]), fmaxf(rmax[2], rmax[3]));
  float scale = 2.0f / (pmax - pmin);

  f32x4 pv = *(const f32x4*)(ppg + (size_t)row * DD + d0);
  f32x4 o4;
  o4[0] = pv[0] + (scale * (a0 - pmin) - 1.0f);
  o4[1] = pv[1] + (scale * (a1 - pmin) - 1.0f);
  o4[2] = pv[2] + (scale * (a2 - pmin) - 1.0f);
  o4[3] = pv[3] + (scale * (a3 - pmin) - 1.0f);
  *(f32x4*)(out + (size_t)row * DD + d0) = o4;
}

// ---------- Kernel 5: deterministic final reduction -------------------------
__global__ __launch_bounds__(256) void finalize_kernel(const float* __restrict__ ws,
                                                       float* __restrict__ out) {
  int t = threadIdx.x;
  const float* ss = ws + WS_SCORE;
  const float* ee = ws + WS_ENT;
  float s = 0.f, e = 0.f;
  for (int i = t; i < BZ; i += 256) { s += ss[i]; e += ee[i]; }
  __shared__ float rs[4], re[4];
  #pragma unroll
  for (int o = 32; o > 0; o >>= 1) { s += __shfl_down(s, o); e += __shfl_down(e, o); }
  if ((t & 63) == 0) { rs[t >> 6] = s; re[t >> 6] = e; }
  __syncthreads();
  if (t == 0) {
    float sT = rs[0] + rs[1] + rs[2] + rs[3];
    float eT = re[0] + re[1] + re[2] + re[3];
    out[(size_t)BZ * DD + 0] = sT / (float)(BZ * KSEL);
    out[(size_t)BZ * DD + 1] = eT / (float)BZ;
  }
}

extern "C" void kernel_launch(void* const* d_in, const int* in_sizes, int n_in,
                              void* d_out, int out_size, void* d_ws, size_t ws_size,
                              hipStream_t stream) {
  const float* ppg  = (const float*)d_in[0];
  const float* keys = (const float*)d_in[1];
  const float* pool = (const float*)d_in[2];
  const float* cw   = (const float*)d_in[3];
  const float* cb   = (const float*)d_in[4];
  float* out = (float*)d_out;
  float* ws  = (float*)d_ws;

  hipLaunchKernelGGL(convert_kernel, dim3(PP + BZ), dim3(256), 0, stream, ppg, keys, ws);
  hipLaunchKernelGGL(pcnn_kernel, dim3(PP), dim3(256), 0, stream, pool, cw, cb, ws);
  hipLaunchKernelGGL(gemm_mfma, dim3((BZ / 128) * (PP / 128)), dim3(256), 0, stream, ws, out);
  hipLaunchKernelGGL(topk_wave_kernel, dim3(BZ / 4), dim3(256), 0, stream, out, ws);
  hipLaunchKernelGGL(prompt_kernel, dim3(BZ), dim3(256), 0, stream, ppg, ws, ws, out);
  hipLaunchKernelGGL(finalize_kernel, dim3(1), dim3(256), 0, stream, ws, out);
}

// Round 17
// 124.569 us; speedup vs baseline: 1.0190x; 1.0190x over previous
//
#include <hip/hip_runtime.h>
#include <hip/hip_bf16.h>

#define BZ 8192
#define PP 1024
#define DD 1024
#define KSEL 8

typedef unsigned short u16;
typedef unsigned long long u64;
typedef __attribute__((ext_vector_type(8))) short bf16x8;
typedef __attribute__((ext_vector_type(4))) float f32x4;

// ws layout (floats):
//   [0,1024)       inv-norm keys
//   [1024,9216)    inv-norm ppg
//   [9216,17408)   per-row top-8 score sum
//   [17408,25600)  per-row entropy
//   [25600,91136)  top-8 indices (ints)
//   byte 368640   .. 38117376 : bf16 A_hi, A_lo (16MB each), B_hi, B_lo (2MB each)
//   byte 38117376 .. 42311680 : pcnn = relu(conv(pool)) fp32 [1024][1024] (4MB)
// C (fp32 cos matrix) lives in d_out; topk reads it, prompt overwrites it.
#define WS_INVK 0
#define WS_INVP 1024
#define WS_SCORE 9216
#define WS_ENT 17408
#define WS_IDX 25600
#define WS_BF16_BYTE 368640ull
#define WS_PCNN_BYTE 38117376ull

__device__ __forceinline__ u16 f2bf(float x) {
  __hip_bfloat16 h = __float2bfloat16(x);
  return *(u16*)&h;
}
__device__ __forceinline__ float bf2f(u16 u) {
  __hip_bfloat16 h; *(u16*)&h = u;
  return __bfloat162float(h);
}
__device__ __forceinline__ void gll16(const void* g, void* l) {
  __builtin_amdgcn_global_load_lds((__attribute__((address_space(1))) void*)g,
                                   (__attribute__((address_space(3))) void*)l, 16, 0, 0);
}

// ---------- Kernel 1: fused fp32->bf16 hi/lo conversion + inverse norms ------
// (verbatim r3 — validated)
__global__ __launch_bounds__(256) void convert_kernel(const float* __restrict__ ppg,
                                                      const float* __restrict__ keys,
                                                      float* __restrict__ ws) {
  u16* Ahi = (u16*)((char*)ws + WS_BF16_BYTE);
  u16* Alo = Ahi + 8388608;
  u16* Bhi = Alo + 8388608;
  u16* Blo = Bhi + 1048576;

  int blk = blockIdx.x;
  const float* src; u16 *hi, *lo; float* invdst;
  if (blk < PP) {
    src = keys + (size_t)blk * DD;
    hi = Bhi + (size_t)blk * DD; lo = Blo + (size_t)blk * DD;
    invdst = ws + WS_INVK + blk;
  } else {
    int r = blk - PP;
    src = ppg + (size_t)r * DD;
    hi = Ahi + (size_t)r * DD; lo = Alo + (size_t)r * DD;
    invdst = ws + WS_INVP + r;
  }
  int t = threadIdx.x;
  float4 v = ((const float4*)src)[t];
  float x[4] = {v.x, v.y, v.z, v.w};
  u16 h4[4], l4[4];
  float s = 0.f;
  #pragma unroll
  for (int j = 0; j < 4; ++j) {
    h4[j] = f2bf(x[j]);
    l4[j] = f2bf(x[j] - bf2f(h4[j]));
    s += x[j] * x[j];
  }
  *(ushort4*)(hi + t * 4) = *(ushort4*)h4;
  *(ushort4*)(lo + t * 4) = *(ushort4*)l4;

  __shared__ float red[4];
  #pragma unroll
  for (int o = 32; o > 0; o >>= 1) s += __shfl_down(s, o);
  if ((t & 63) == 0) red[t >> 6] = s;
  __syncthreads();
  if (t == 0) {
    float tot = red[0] + red[1] + red[2] + red[3];
    *invdst = 1.0f / fmaxf(sqrtf(tot), 1e-8f);
  }
}

// ---------- Kernel 1b: pcnn = relu(conv(pool)) precompute (r16 — validated) --
__global__ __launch_bounds__(256) void pcnn_kernel(const float* __restrict__ pool,
                                                   const float* __restrict__ cw,
                                                   const float* __restrict__ cb,
                                                   float* __restrict__ ws) {
  float* pcnn = (float*)((char*)ws + WS_PCNN_BYTE);
  int row = blockIdx.x;
  int t = threadIdx.x;
  int d0 = t * 4;
  const float* src = pool + (size_t)row * DD;
  float w0 = cw[0], w1 = cw[1], w2 = cw[2], bb = cb[0];

  f32x4 x = *(const f32x4*)(src + d0);
  float xm = (d0 > 0) ? src[d0 - 1] : 0.f;
  float xp = (d0 + 4 < DD) ? src[d0 + 4] : 0.f;
  float y0 = fmaf(w0, xm,   fmaf(w1, x[0], fmaf(w2, x[1], bb)));
  float y1 = fmaf(w0, x[0], fmaf(w1, x[1], fmaf(w2, x[2], bb)));
  float y2 = fmaf(w0, x[1], fmaf(w1, x[2], fmaf(w2, x[3], bb)));
  float y3 = fmaf(w0, x[2], fmaf(w1, x[3], fmaf(w2, xp,   bb)));
  f32x4 o4;
  o4[0] = fmaxf(y0, 0.f);
  o4[1] = fmaxf(y1, 0.f);
  o4[2] = fmaxf(y2, 0.f);
  o4[3] = fmaxf(y3, 0.f);
  *(f32x4*)(pcnn + (size_t)row * DD + d0) = o4;
}

// ---------- Kernel 2: 3-pass bf16 hi/lo MFMA GEMM -> fp32 cos in d_out ------
// (verbatim r15/r9 BK=64 — validated at 55.1 µs; r16's BK=32 regressed:
//  grid-limited to 2 blocks/CU, so halving LDS only doubled barriers)
#define LDS_AH 0
#define LDS_AL 8192
#define LDS_BH 16384
#define LDS_BL 24576

__global__ __launch_bounds__(256, 2) void gemm_mfma(const float* __restrict__ ws_ro,
                                                    float* __restrict__ C) {
  const u16* Ahi = (const u16*)((const char*)ws_ro + WS_BF16_BYTE);
  const u16* Alo = Ahi + 8388608;
  const u16* Bhi = Alo + 8388608;
  const u16* Blo = Bhi + 1048576;

  __shared__ u16 lds[32768];  // 64 KB

  int t = threadIdx.x;
  int wid = t >> 6, lane = t & 63;
  int lr = lane & 15, lg = lane >> 4;

  int orig = blockIdx.x;
  int wg = (orig & 7) * 64 + (orig >> 3);
  int bm0 = (wg >> 3) * 128;
  int bn0 = (wg & 7) * 128;
  int wm = wid >> 1, wn = wid & 1;

  size_t offA[4], offB[4];
  int ldso[4];
  #pragma unroll
  for (int r = 0; r < 4; ++r) {
    int s = r * 256 + t;
    int row = s >> 3, g = s & 7;
    offA[r] = (size_t)(bm0 + row) * DD + g * 8;
    offB[r] = (size_t)(bn0 + row) * DD + g * 8;
    ldso[r] = (r * 256 + wid * 64) * 8;
  }

  f32x4 acc[4][4] = {};

  for (int kt = 0; kt < 16; ++kt) {
    int k0 = kt * 64;
    #pragma unroll
    for (int r = 0; r < 4; ++r) {
      gll16(Ahi + offA[r] + k0, &lds[LDS_AH + ldso[r]]);
      gll16(Alo + offA[r] + k0, &lds[LDS_AL + ldso[r]]);
      gll16(Bhi + offB[r] + k0, &lds[LDS_BH + ldso[r]]);
      gll16(Blo + offB[r] + k0, &lds[LDS_BL + ldso[r]]);
    }
    __syncthreads();

    #pragma unroll
    for (int kh = 0; kh < 2; ++kh) {
      bf16x8 ah[4], al[4], bh[4], bl[4];
      #pragma unroll
      for (int i = 0; i < 4; ++i) {
        int off = (wm * 64 + i * 16 + lr) * 64 + kh * 32 + lg * 8;
        ah[i] = *(const bf16x8*)&lds[LDS_AH + off];
        al[i] = *(const bf16x8*)&lds[LDS_AL + off];
      }
      #pragma unroll
      for (int j = 0; j < 4; ++j) {
        int off = (wn * 64 + j * 16 + lr) * 64 + kh * 32 + lg * 8;
        bh[j] = *(const bf16x8*)&lds[LDS_BH + off];
        bl[j] = *(const bf16x8*)&lds[LDS_BL + off];
      }
      #pragma unroll
      for (int i = 0; i < 4; ++i)
        #pragma unroll
        for (int j = 0; j < 4; ++j) {
          acc[i][j] = __builtin_amdgcn_mfma_f32_16x16x32_bf16(ah[i], bh[j], acc[i][j], 0, 0, 0);
          acc[i][j] = __builtin_amdgcn_mfma_f32_16x16x32_bf16(ah[i], bl[j], acc[i][j], 0, 0, 0);
          acc[i][j] = __builtin_amdgcn_mfma_f32_16x16x32_bf16(al[i], bh[j], acc[i][j], 0, 0, 0);
        }
    }
    __syncthreads();
  }

  const float* invP = ws_ro + WS_INVP;
  const float* invK = ws_ro + WS_INVK;
  #pragma unroll
  for (int i = 0; i < 4; ++i) {
    #pragma unroll
    for (int q = 0; q < 4; ++q) {
      int row = bm0 + wm * 64 + i * 16 + lg * 4 + q;
      float ip = invP[row];
      #pragma unroll
      for (int j = 0; j < 4; ++j) {
        int col = bn0 + wn * 64 + j * 16 + lr;
        C[(size_t)row * PP + col] = acc[i][j][q] * ip * invK[col];
      }
    }
  }
}

// ---------- Kernel 3: wave-per-row top-8 + entropy (u64 keys, r15-validated) -
__global__ __launch_bounds__(256) void topk_wave_kernel(const float* __restrict__ cosm,
                                                        float* __restrict__ ws) {
  int wid = threadIdx.x >> 6, lane = threadIdx.x & 63;
  int row = blockIdx.x * 4 + wid;
  const float* crow = cosm + (size_t)row * PP;

  float c[16];
  #pragma unroll
  for (int p = 0; p < 4; ++p) {
    f32x4 v = *(const f32x4*)(crow + p * 256 + lane * 4);
    c[p * 4 + 0] = v[0]; c[p * 4 + 1] = v[1]; c[p * 4 + 2] = v[2]; c[p * 4 + 3] = v[3];
  }

  float z = 0.f, w = 0.f;
  #pragma unroll
  for (int l = 0; l < 16; ++l) {
    float s = 1.0f - c[l];
    float e = __expf(s - 2.0f);
    z += e; w += s * e;
  }
  #pragma unroll
  for (int o = 1; o < 64; o <<= 1) { z += __shfl_xor(z, o); w += __shfl_xor(w, o); }
  if (lane == 0) ws[WS_ENT + row] = 2.0f + __logf(z) - w / z;

  u64 k[16];
  #pragma unroll
  for (int l = 0; l < 16; ++l) {
    unsigned fb = __builtin_bit_cast(unsigned, c[l]);
    unsigned mv = fb ^ ((unsigned)((int)fb >> 31) | 0x80000000u);
    int g = ((l >> 2) << 8) | (lane << 2) | (l & 3);
    k[l] = ((u64)mv << 10) | (unsigned)(1023 - g);
  }

  float score_sum = 0.f;
  int myidx = 0;
  #pragma unroll
  for (int it = 0; it < KSEL; ++it) {
    u64 m = k[0];
    #pragma unroll
    for (int l = 1; l < 16; ++l) m = (k[l] > m) ? k[l] : m;
    #pragma unroll
    for (int o = 1; o < 64; o <<= 1) {
      u64 p = __shfl_xor(m, o);
      m = (p > m) ? p : m;
    }
    unsigned mv2 = (unsigned)(m >> 10);
    unsigned fb2 = mv2 ^ ((mv2 & 0x80000000u) ? 0x80000000u : 0xFFFFFFFFu);
    score_sum += 1.0f - __builtin_bit_cast(float, fb2);
    if (lane == it) myidx = 1023 - (int)(m & 1023u);
    #pragma unroll
    for (int l = 0; l < 16; ++l) k[l] = (k[l] == m) ? 0ull : k[l];
  }
  if (lane == 0) ws[WS_SCORE + row] = score_sum;
  if (lane < KSEL) ((int*)(ws + WS_IDX))[row * KSEL + lane] = myidx;
}

// ---------- Kernel 4: block-per-row prompt (pcnn gather, r16 — validated) ---
__global__ __launch_bounds__(256) void prompt_kernel(const float* __restrict__ ppg,
                                                     const float* __restrict__ ws_ro,
                                                     const float* __restrict__ ws,
                                                     float* __restrict__ out) {
  const float* pcnn = (const float*)((const char*)ws_ro + WS_PCNN_BYTE);
  int row = blockIdx.x;
  int t = threadIdx.x;
  const int* idx = (const int*)(ws + WS_IDX) + row * KSEL;
  int d0 = t * 4;

  float a0 = 0.f, a1 = 0.f, a2 = 0.f, a3 = 0.f;
  #pragma unroll
  for (int j = 0; j < KSEL; ++j) {
    int r = idx[j];
    f32x4 x = *(const f32x4*)(pcnn + (size_t)r * DD + d0);
    a0 += x[0]; a1 += x[1]; a2 += x[2]; a3 += x[3];
  }
  a0 *= 0.125f; a1 *= 0.125f; a2 *= 0.125f; a3 *= 0.125f;

  __shared__ float rmin[4], rmax[4];
  float lmin = fminf(fminf(a0, a1), fminf(a2, a3));
  float lmax = fmaxf(fmaxf(a0, a1), fmaxf(a2, a3));
  #pragma unroll
  for (int o = 32; o > 0; o >>= 1) {
    lmin = fminf(lmin, __shfl_down(lmin, o));
    lmax = fmaxf(lmax, __shfl_down(lmax, o));
  }
  if ((t & 63) == 0) { rmin[t >> 6] = lmin; rmax[t >> 6] = lmax; }
  __syncthreads();
  float pmin = fminf(fminf(rmin[0], rmin[1]), fminf(rmin[2], rmin[3]));
  float pmax = fmaxf(fmaxf(rmax[0], rmax[1]), fmaxf(rmax[2], rmax[3]));
  float scale = 2.0f / (pmax - pmin);

  f32x4 pv = *(const f32x4*)(ppg + (size_t)row * DD + d0);
  f32x4 o4;
  o4[0] = pv[0] + (scale * (a0 - pmin) - 1.0f);
  o4[1] = pv[1] + (scale * (a1 - pmin) - 1.0f);
  o4[2] = pv[2] + (scale * (a2 - pmin) - 1.0f);
  o4[3] = pv[3] + (scale * (a3 - pmin) - 1.0f);
  *(f32x4*)(out + (size_t)row * DD + d0) = o4;
}

// ---------- Kernel 5: deterministic final reduction -------------------------
__global__ __launch_bounds__(256) void finalize_kernel(const float* __restrict__ ws,
                                                       float* __restrict__ out) {
  int t = threadIdx.x;
  const float* ss = ws + WS_SCORE;
  const float* ee = ws + WS_ENT;
  float s = 0.f, e = 0.f;
  for (int i = t; i < BZ; i += 256) { s += ss[i]; e += ee[i]; }
  __shared__ float rs[4], re[4];
  #pragma unroll
  for (int o = 32; o > 0; o >>= 1) { s += __shfl_down(s, o); e += __shfl_down(e, o); }
  if ((t & 63) == 0) { rs[t >> 6] = s; re[t >> 6] = e; }
  __syncthreads();
  if (t == 0) {
    float sT = rs[0] + rs[1] + rs[2] + rs[3];
    float eT = re[0] + re[1] + re[2] + re[3];
    out[(size_t)BZ * DD + 0] = sT / (float)(BZ * KSEL);
    out[(size_t)BZ * DD + 1] = eT / (float)BZ;
  }
}

extern "C" void kernel_launch(void* const* d_in, const int* in_sizes, int n_in,
                              void* d_out, int out_size, void* d_ws, size_t ws_size,
                              hipStream_t stream) {
  const float* ppg  = (const float*)d_in[0];
  const float* keys = (const float*)d_in[1];
  const float* pool = (const float*)d_in[2];
  const float* cw   = (const float*)d_in[3];
  const float* cb   = (const float*)d_in[4];
  float* out = (float*)d_out;
  float* ws  = (float*)d_ws;

  hipLaunchKernelGGL(convert_kernel, dim3(PP + BZ), dim3(256), 0, stream, ppg, keys, ws);
  hipLaunchKernelGGL(pcnn_kernel, dim3(PP), dim3(256), 0, stream, pool, cw, cb, ws);
  hipLaunchKernelGGL(gemm_mfma, dim3((BZ / 128) * (PP / 128)), dim3(256), 0, stream, ws, out);
  hipLaunchKernelGGL(topk_wave_kernel, dim3(BZ / 4), dim3(256), 0, stream, out, ws);
  hipLaunchKernelGGL(prompt_kernel, dim3(BZ), dim3(256), 0, stream, ppg, ws, ws, out);
  hipLaunchKernelGGL(finalize_kernel, dim3(1), dim3(256), 0, stream, ws, out);
}